// Round 8
// baseline (499.227 us; speedup 1.0000x reference)
//
#include <hip/hip_runtime.h>

#define NNODES 50000
#define NEDGES 800000
#define HD 128
#define NG 512
#define BN_EPS 1e-5f
#define GEMM_NB 782          // 64-row tiles
#define NSPLIT 16            // stats atomic split
#define AROW 136             // padded A-tile row, ushorts (272 B) -> 2-way banks only

typedef short bf16x8 __attribute__((ext_vector_type(8)));
typedef float floatx4 __attribute__((ext_vector_type(4)));

union U16 { uint4 u; bf16x8 h; };

__device__ __forceinline__ ushort f2bf(float f) {
    unsigned u = __float_as_uint(f);
    return (ushort)((u + 0x7fffu + ((u >> 16) & 1u)) >> 16);
}
__device__ __forceinline__ void unpack8(const uint4& u, float* f) {
    const unsigned* w = (const unsigned*)&u;
#pragma unroll
    for (int i = 0; i < 4; ++i) {
        f[2 * i]     = __uint_as_float(w[i] << 16);
        f[2 * i + 1] = __uint_as_float(w[i] & 0xffff0000u);
    }
}
__device__ __forceinline__ uint4 pack8(const float* f) {
    uint4 o;
    unsigned* w = (unsigned*)&o;
#pragma unroll
    for (int i = 0; i < 4; ++i)
        w[i] = (unsigned)f2bf(f[2 * i]) | ((unsigned)f2bf(f[2 * i + 1]) << 16);
    return o;
}

// ---------------- CSR build ----------------

__global__ void hist_kernel(const int* __restrict__ dst, int* __restrict__ cnt, int n) {
    int i = blockIdx.x * 256 + threadIdx.x;
    if (i < n) atomicAdd(&cnt[dst[i]], 1);
}

__global__ void scan1_kernel(const int* __restrict__ cnt, int* __restrict__ incl,
                             int* __restrict__ bsum, int n) {
    __shared__ int s[1024];
    int i = blockIdx.x * 1024 + threadIdx.x;
    int v = (i < n) ? cnt[i] : 0;
    s[threadIdx.x] = v;
    __syncthreads();
    for (int off = 1; off < 1024; off <<= 1) {
        int add = (threadIdx.x >= off) ? s[threadIdx.x - off] : 0;
        __syncthreads();
        s[threadIdx.x] += add;
        __syncthreads();
    }
    if (i < n) incl[i] = s[threadIdx.x];
    if (threadIdx.x == 1023) bsum[blockIdx.x] = s[1023];
}

__global__ void scan2_kernel(const int* __restrict__ bsum, int* __restrict__ boffs, int nb) {
    __shared__ int s[64];
    int v = (threadIdx.x < nb) ? bsum[threadIdx.x] : 0;
    s[threadIdx.x] = v;
    __syncthreads();
    for (int off = 1; off < 64; off <<= 1) {
        int add = (threadIdx.x >= off) ? s[threadIdx.x - off] : 0;
        __syncthreads();
        s[threadIdx.x] += add;
        __syncthreads();
    }
    if (threadIdx.x < nb) boffs[threadIdx.x] = s[threadIdx.x] - v;  // exclusive
}

__global__ void scan3_kernel(const int* __restrict__ incl, const int* __restrict__ boffs,
                             int* __restrict__ rowp, int n) {
    int i = blockIdx.x * 256 + threadIdx.x;
    if (i < n) rowp[i + 1] = incl[i] + boffs[i >> 10];
    if (i == 0) rowp[0] = 0;
}

__global__ void build_kernel(const int* __restrict__ src, const int* __restrict__ dst,
                             const int* __restrict__ rowp, int* __restrict__ fill,
                             int* __restrict__ colv, int n) {
    int i = blockIdx.x * 256 + threadIdx.x;
    if (i < n) {
        int d = dst[i];
        int pos = rowp[d] + atomicAdd(&fill[d], 1);
        colv[pos] = src[i];
    }
}

// ---------------- fp32 -> bf16 convert ----------------

__global__ void cvt_kernel(const float* __restrict__ x, ushort* __restrict__ xb, int n4) {
    int i = blockIdx.x * 256 + threadIdx.x;
    if (i < n4) {
        float4 v = ((const float4*)x)[i];
        ushort4 o;
        o.x = f2bf(v.x); o.y = f2bf(v.y); o.z = f2bf(v.z); o.w = f2bf(v.w);
        ((ushort4*)xb)[i] = o;
    }
}

// ---------------- pack weights into MFMA B-fragment order (bf16) ----------------

struct WP6 { const float* w[6]; };

__global__ void wfrag_kernel(WP6 p, ushort* __restrict__ wf) {
    const float* W = p.w[blockIdx.x];
    ushort* o = wf + (size_t)blockIdx.x * 16384;
    for (int i = threadIdx.x; i < 16384; i += 256) {
        int j = i & 7, lane = (i >> 3) & 63, kc = (i >> 9) & 3, ct = i >> 11;
        int k = kc * 32 + (lane >> 4) * 8 + j;
        int n = ct * 16 + (lane & 15);
        o[i] = f2bf(W[k * HD + n]);
    }
}

// ---------------- fused (gather?) + MFMA GEMM + (stats | BN-prologue) + (readout) ----
// 782 blocks x 256 threads; block b computes rows [b*64, b*64+64).
// GATHER: A = H[row] + sum_{nbr} H[nbr], gathered into padded LDS tile.
// !GATHER: A loaded direct from global (registers), PRE_BN applies BN+relu first.
// C stored coalesced via LDS round-trip. STATS: register-accumulated col sums,
// 16-way-split atomics. READOUT: per-segment atomicAdd, no C store.

template <bool GATHER, bool STATS, bool PRE_BN, bool READOUT>
__global__ __launch_bounds__(256, 3) void fused_gemm_kernel(
    const ushort* __restrict__ H, const int* __restrict__ rowp,
    const int* __restrict__ colv,
    const ushort* __restrict__ Wf, const float* __restrict__ bias,
    ushort* __restrict__ out,
    const float* __restrict__ gamma, const float* __restrict__ beta,
    float* __restrict__ ssum_p, float* __restrict__ ssq_p,
    const int* __restrict__ gptr, float* __restrict__ gout, int nrows) {
    __shared__ ushort bs[16384];       // 32 KB B-fragments; aliased by reds/redq later
    __shared__ ushort abuf[64 * AROW]; // 17 KB padded A tile / C tile
    __shared__ float sca[HD];
    __shared__ float shf[HD];
    const int t = threadIdx.x;
    const int wave = t >> 6, lane = t & 63;
    const int quad = lane >> 4, l16 = lane & 15;
    const int row0 = blockIdx.x * 64;

    // stage B into LDS
    {
        const uint4* g = (const uint4*)Wf;
        uint4 v[8];
#pragma unroll
        for (int i = 0; i < 8; ++i) v[i] = g[i * 256 + t];
        uint4* s = (uint4*)bs;
#pragma unroll
        for (int i = 0; i < 8; ++i) s[i * 256 + t] = v[i];
    }

    // BN finalize from split raw stats (stream-ordered complete)
    if (PRE_BN && t < HD) {
        float s = 0.f, q = 0.f;
#pragma unroll
        for (int i = 0; i < NSPLIT; ++i) { s += ssum_p[i * HD + t]; q += ssq_p[i * HD + t]; }
        float mean = s / (float)nrows;
        float var = q / (float)nrows - mean * mean;
        float rstd = rsqrtf(var + BN_EPS);
        float sc = gamma[t] * rstd;
        sca[t] = sc;
        shf[t] = beta[t] - mean * sc;
    }

    uint4 a_cur[4];
    if (GATHER) {
        // gather+sum: 8 lanes per row, 32 B (2 uint4) per lane, fp32 accumulate
        uint4* a4 = (uint4*)abuf;
        const uint4* hp = (const uint4*)H;
#pragma unroll
        for (int half = 0; half < 2; ++half) {
            int rl = half * 32 + (t >> 3);       // local row 0..63
            int r = row0 + rl;
            int p = t & 7;                       // 32B chunk index
            float a[16];
            if (r < nrows) {
                size_t base = (size_t)r * 16 + p * 2;
                uint4 v0 = hp[base], v1 = hp[base + 1];
                unpack8(v0, a);
                unpack8(v1, a + 8);
                int beg = rowp[r], end = rowp[r + 1];
                for (int j = beg; j < end; ++j) {
                    size_t sb = (size_t)colv[j] * 16 + p * 2;
                    uint4 w0 = hp[sb], w1 = hp[sb + 1];
                    float b[16];
                    unpack8(w0, b);
                    unpack8(w1, b + 8);
#pragma unroll
                    for (int i = 0; i < 16; ++i) a[i] += b[i];
                }
            } else {
#pragma unroll
                for (int i = 0; i < 16; ++i) a[i] = 0.f;
            }
            a4[rl * (AROW / 8) + p * 2]     = pack8(a);
            a4[rl * (AROW / 8) + p * 2 + 1] = pack8(a + 8);
        }
    } else {
        int rowA = row0 + wave * 16 + l16;
        bool ok = rowA < nrows;
        const ushort* ap = H + (size_t)rowA * HD + quad * 8;
#pragma unroll
        for (int kc = 0; kc < 4; ++kc)
            a_cur[kc] = ok ? *(const uint4*)(ap + kc * 32) : make_uint4(0, 0, 0, 0);
    }

    __syncthreads();

    floatx4 zf = {0.f, 0.f, 0.f, 0.f};
    floatx4 acc[8];
#pragma unroll
    for (int i = 0; i < 8; ++i) acc[i] = zf;

    const uint4* B4 = (const uint4*)bs;
    const uint4* a4 = (const uint4*)abuf;
    const int rowL = wave * 16 + l16;

#pragma unroll
    for (int kc = 0; kc < 4; ++kc) {
        U16 au;
        if (GATHER) {
            au.u = a4[rowL * (AROW / 8) + kc * 4 + quad];
        } else {
            au.u = a_cur[kc];
            if (PRE_BN) {
                float f[8];
                unpack8(au.u, f);
                int kb = kc * 32 + quad * 8;
                float4 s0 = ((const float4*)(sca + kb))[0];
                float4 s1 = ((const float4*)(sca + kb))[1];
                float4 h0 = ((const float4*)(shf + kb))[0];
                float4 h1 = ((const float4*)(shf + kb))[1];
                f[0] = fmaxf(fmaf(f[0], s0.x, h0.x), 0.f);
                f[1] = fmaxf(fmaf(f[1], s0.y, h0.y), 0.f);
                f[2] = fmaxf(fmaf(f[2], s0.z, h0.z), 0.f);
                f[3] = fmaxf(fmaf(f[3], s0.w, h0.w), 0.f);
                f[4] = fmaxf(fmaf(f[4], s1.x, h1.x), 0.f);
                f[5] = fmaxf(fmaf(f[5], s1.y, h1.y), 0.f);
                f[6] = fmaxf(fmaf(f[6], s1.z, h1.z), 0.f);
                f[7] = fmaxf(fmaf(f[7], s1.w, h1.w), 0.f);
                au.u = pack8(f);
            }
        }
#pragma unroll
        for (int ct = 0; ct < 8; ++ct) {
            U16 bu;
            bu.u = B4[(ct * 4 + kc) * 64 + lane];
            acc[ct] = __builtin_amdgcn_mfma_f32_16x16x32_bf16(au.h, bu.h, acc[ct], 0, 0, 0);
        }
    }

    // C/D layout: col = ct*16 + l16, row = row0 + wave*16 + quad*4 + reg
    const int r_base = row0 + wave * 16 + quad * 4;

    if (READOUT) {
        int segr[4] = {-1, -1, -1, -1};
        if (r_base < nrows) {
            int lo = 0, hi = NG - 1;
            while (lo < hi) {
                int mid = (lo + hi) >> 1;
                if (r_base >= gptr[mid + 1]) lo = mid + 1; else hi = mid;
            }
            int sg = lo;
#pragma unroll
            for (int reg = 0; reg < 4; ++reg) {
                int rw = r_base + reg;
                if (rw < nrows) {
                    while (rw >= gptr[sg + 1]) ++sg;
                    segr[reg] = sg;
                }
            }
        }
#pragma unroll
        for (int ct = 0; ct < 8; ++ct) {
            int col = ct * 16 + l16;
            float b = bias[col];
            float run = 0.f;
            int cur = segr[0];
#pragma unroll
            for (int reg = 0; reg < 4; ++reg) {
                if (segr[reg] != cur) {
                    if (cur >= 0 && run != 0.f) atomicAdd(&gout[cur * HD + col], run);
                    run = 0.f;
                    cur = segr[reg];
                }
                if (cur >= 0) run += fmaxf(acc[ct][reg] + b, 0.f);
            }
            if (cur >= 0 && run != 0.f) atomicAdd(&gout[cur * HD + col], run);
        }
        return;
    }

    // C epilogue: write own 16-row band of abuf (safe: this wave's A reads done)
    float s_acc[8], q_acc[8];
    const int lrow = wave * 16 + quad * 4;
#pragma unroll
    for (int ct = 0; ct < 8; ++ct) {
        int col = ct * 16 + l16;
        float b = bias[col];
        float s = 0.f, q = 0.f;
#pragma unroll
        for (int reg = 0; reg < 4; ++reg) {
            float v = acc[ct][reg] + b;
            if (!STATS) v = fmaxf(v, 0.f);  // GEMM-B: relu; GEMM-A: raw pre-BN
            abuf[(lrow + reg) * AROW + col] = f2bf(v);
            if (STATS && (r_base + reg) < nrows) { s += v; q += v * v; }
        }
        s_acc[ct] = s; q_acc[ct] = q;
    }

    __syncthreads();  // all waves: MFMA B-reads done (bs free), C tile complete

    // stats partials into bs-aliased reds/redq
    float* reds = (float*)bs;          // [4][128]
    float* redq = ((float*)bs) + 512;  // [4][128]
    if (STATS) {
#pragma unroll
        for (int ct = 0; ct < 8; ++ct) {
            float s = s_acc[ct], q = q_acc[ct];
            s += __shfl_xor(s, 16); s += __shfl_xor(s, 32);
            q += __shfl_xor(q, 16); q += __shfl_xor(q, 32);
            if (quad == 0) { reds[wave * HD + ct * 16 + l16] = s; redq[wave * HD + ct * 16 + l16] = q; }
        }
    }

    // coalesced C store from abuf
    {
        const uint4* c4 = (const uint4*)abuf;
        uint4* o4 = (uint4*)out;
#pragma unroll
        for (int i = 0; i < 4; ++i) {
            int f = t * 4 + i;
            int row = f >> 4;
            int part = f & 15;
            if (row0 + row < nrows) o4[(size_t)(row0 + row) * 16 + part] = c4[row * (AROW / 8) + part];
        }
    }

    if (STATS) {
        __syncthreads();
        int slot = (blockIdx.x & (NSPLIT - 1)) * HD;
        if (t < HD) {
            atomicAdd(&ssum_p[slot + t], reds[t] + reds[HD + t] + reds[2 * HD + t] + reds[3 * HD + t]);
        } else if (t < 2 * HD) {
            int c = t - HD;
            atomicAdd(&ssq_p[slot + c], redq[c] + redq[HD + c] + redq[2 * HD + c] + redq[3 * HD + c]);
        }
    }
}

// ---------------- launch ----------------

extern "C" void kernel_launch(void* const* d_in, const int* in_sizes, int n_in,
                              void* d_out, int out_size, void* d_ws, size_t ws_size,
                              hipStream_t stream) {
    const float* x = (const float*)d_in[0];
    const int* esrc = (const int*)d_in[1];
    const int* edst = (const int*)d_in[2];
    const int* gptr = (const int*)d_in[3];
    const float* wA[3] = {(const float*)d_in[4], (const float*)d_in[10], (const float*)d_in[16]};
    const float* bA[3] = {(const float*)d_in[5], (const float*)d_in[11], (const float*)d_in[17]};
    const float* gm[3] = {(const float*)d_in[6], (const float*)d_in[12], (const float*)d_in[18]};
    const float* bt[3] = {(const float*)d_in[7], (const float*)d_in[13], (const float*)d_in[19]};
    const float* wB[3] = {(const float*)d_in[8], (const float*)d_in[14], (const float*)d_in[20]};
    const float* bB[3] = {(const float*)d_in[9], (const float*)d_in[15], (const float*)d_in[21]};

    char* w = (char*)d_ws;
    ushort* xb   = (ushort*)w; w += (size_t)NNODES * HD * 2;  // 12.8 MB
    ushort* zbb  = (ushort*)w; w += (size_t)NNODES * HD * 2;
    ushort* hbb  = (ushort*)w; w += (size_t)NNODES * HD * 2;
    ushort* wf   = (ushort*)w; w += (size_t)6 * 16384 * 2;    // 192 KB
    int* colv  = (int*)w;   w += (size_t)NEDGES * 4;
    int* incl  = (int*)w;   w += (size_t)NNODES * 4;
    int* rowp  = (int*)w;   w += ((size_t)(NNODES + 1) * 4 + 15) & ~(size_t)15;
    int* bsum  = (int*)w;   w += 64 * 4;
    int* boffs = (int*)w;   w += 64 * 4;
    // ---- zero region ----
    char* zero_base = w;
    int* cnt   = (int*)w;   w += (size_t)NNODES * 4;
    int* fill  = (int*)w;   w += (size_t)NNODES * 4;
    float* ssum_p = (float*)w; w += 3 * NSPLIT * 128 * 4;
    float* ssq_p  = (float*)w; w += 3 * NSPLIT * 128 * 4;
    size_t zero_bytes = (size_t)(w - zero_base);

    hipMemsetAsync(zero_base, 0, zero_bytes, stream);
    hipMemsetAsync(d_out, 0, (size_t)NG * HD * 4, stream);

    // CSR by destination
    hist_kernel<<<(NEDGES + 255) / 256, 256, 0, stream>>>(edst, cnt, NEDGES);
    int nsb = (NNODES + 1023) / 1024;  // 49
    scan1_kernel<<<nsb, 1024, 0, stream>>>(cnt, incl, bsum, NNODES);
    scan2_kernel<<<1, 64, 0, stream>>>(bsum, boffs, nsb);
    scan3_kernel<<<(NNODES + 255) / 256, 256, 0, stream>>>(incl, boffs, rowp, NNODES);
    build_kernel<<<(NEDGES + 255) / 256, 256, 0, stream>>>(esrc, edst, rowp, fill, colv, NEDGES);

    cvt_kernel<<<(NNODES * HD / 4 + 255) / 256, 256, 0, stream>>>(x, xb, NNODES * HD / 4);
    WP6 wp;
    wp.w[0] = wA[0]; wp.w[1] = wB[0]; wp.w[2] = wA[1];
    wp.w[3] = wB[1]; wp.w[4] = wA[2]; wp.w[5] = wB[2];
    wfrag_kernel<<<6, 256, 0, stream>>>(wp, wf);

    const ushort* hin = xb;
    for (int l = 0; l < 3; ++l) {
        // fused aggregation + GEMM-A + stats
        fused_gemm_kernel<true, true, false, false><<<GEMM_NB, 256, 0, stream>>>(
            hin, rowp, colv, wf + (size_t)(2 * l) * 16384, bA[l], zbb,
            nullptr, nullptr, ssum_p + l * NSPLIT * 128, ssq_p + l * NSPLIT * 128,
            nullptr, nullptr, NNODES);
        // BN + GEMM-B (+readout on last layer)
        if (l < 2) {
            fused_gemm_kernel<false, false, true, false><<<GEMM_NB, 256, 0, stream>>>(
                zbb, nullptr, nullptr, wf + (size_t)(2 * l + 1) * 16384, bB[l], hbb,
                gm[l], bt[l], ssum_p + l * NSPLIT * 128, ssq_p + l * NSPLIT * 128,
                nullptr, nullptr, NNODES);
        } else {
            fused_gemm_kernel<false, false, true, true><<<GEMM_NB, 256, 0, stream>>>(
                zbb, nullptr, nullptr, wf + (size_t)(2 * l + 1) * 16384, bB[l], nullptr,
                gm[l], bt[l], ssum_p + l * NSPLIT * 128, ssq_p + l * NSPLIT * 128,
                gptr, (float*)d_out, NNODES);
        }
        hin = hbb;
    }
}

// Round 10
// 458.382 us; speedup vs baseline: 1.0891x; 1.0891x over previous
//
#include <hip/hip_runtime.h>

#define NNODES 50000
#define NEDGES 800000
#define HD 128
#define NG 512
#define BN_EPS 1e-5f
#define NTILE 3125           // 16-row tiles: 50000 = 3125 * 16 exactly
#define NSPLIT 32            // stats atomic split

typedef short bf16x8 __attribute__((ext_vector_type(8)));
typedef float floatx4 __attribute__((ext_vector_type(4)));

union U16 { uint4 u; bf16x8 h; };

__device__ __forceinline__ ushort f2bf(float f) {
    unsigned u = __float_as_uint(f);
    return (ushort)((u + 0x7fffu + ((u >> 16) & 1u)) >> 16);
}
__device__ __forceinline__ void unpack8(const uint4& u, float* f) {
    const unsigned* w = (const unsigned*)&u;
#pragma unroll
    for (int i = 0; i < 4; ++i) {
        f[2 * i]     = __uint_as_float(w[i] << 16);
        f[2 * i + 1] = __uint_as_float(w[i] & 0xffff0000u);
    }
}
__device__ __forceinline__ uint4 pack8(const float* f) {
    uint4 o;
    unsigned* w = (unsigned*)&o;
#pragma unroll
    for (int i = 0; i < 4; ++i)
        w[i] = (unsigned)f2bf(f[2 * i]) | ((unsigned)f2bf(f[2 * i + 1]) << 16);
    return o;
}

// ---------------- CSR build ----------------

__global__ void hist_kernel(const int* __restrict__ dst, int* __restrict__ cnt, int n) {
    int i = blockIdx.x * 256 + threadIdx.x;
    if (i < n) atomicAdd(&cnt[dst[i]], 1);
}

__global__ void scan1_kernel(const int* __restrict__ cnt, int* __restrict__ incl,
                             int* __restrict__ bsum, int n) {
    __shared__ int s[1024];
    int i = blockIdx.x * 1024 + threadIdx.x;
    int v = (i < n) ? cnt[i] : 0;
    s[threadIdx.x] = v;
    __syncthreads();
    for (int off = 1; off < 1024; off <<= 1) {
        int add = (threadIdx.x >= off) ? s[threadIdx.x - off] : 0;
        __syncthreads();
        s[threadIdx.x] += add;
        __syncthreads();
    }
    if (i < n) incl[i] = s[threadIdx.x];
    if (threadIdx.x == 1023) bsum[blockIdx.x] = s[1023];
}

__global__ void scan2_kernel(const int* __restrict__ bsum, int* __restrict__ boffs, int nb) {
    __shared__ int s[64];
    int v = (threadIdx.x < nb) ? bsum[threadIdx.x] : 0;
    s[threadIdx.x] = v;
    __syncthreads();
    for (int off = 1; off < 64; off <<= 1) {
        int add = (threadIdx.x >= off) ? s[threadIdx.x - off] : 0;
        __syncthreads();
        s[threadIdx.x] += add;
        __syncthreads();
    }
    if (threadIdx.x < nb) boffs[threadIdx.x] = s[threadIdx.x] - v;  // exclusive
}

__global__ void scan3_kernel(const int* __restrict__ incl, const int* __restrict__ boffs,
                             int* __restrict__ rowp, int n) {
    int i = blockIdx.x * 256 + threadIdx.x;
    if (i < n) rowp[i + 1] = incl[i] + boffs[i >> 10];
    if (i == 0) rowp[0] = 0;
}

__global__ void build_kernel(const int* __restrict__ src, const int* __restrict__ dst,
                             const int* __restrict__ rowp, int* __restrict__ fill,
                             int* __restrict__ colv, int n) {
    int i = blockIdx.x * 256 + threadIdx.x;
    if (i < n) {
        int d = dst[i];
        int pos = rowp[d] + atomicAdd(&fill[d], 1);
        colv[pos] = src[i];
    }
}

// ---------------- fp32 -> bf16 convert ----------------

__global__ void cvt_kernel(const float* __restrict__ x, ushort* __restrict__ xb, int n4) {
    int i = blockIdx.x * 256 + threadIdx.x;
    if (i < n4) {
        float4 v = ((const float4*)x)[i];
        ushort4 o;
        o.x = f2bf(v.x); o.y = f2bf(v.y); o.z = f2bf(v.z); o.w = f2bf(v.w);
        ((ushort4*)xb)[i] = o;
    }
}

// ---------------- pack weights into MFMA B-fragment order (bf16) ----------------
// B-frag for mfma_f32_16x16x32_bf16: lane reads B[k=quad*8+j][n=l16] for its (ct,kc).
// Wf flat index: ((ct*4+kc)*64 + lane)*8 + j

struct WP6 { const float* w[6]; };

__global__ void wfrag_kernel(WP6 p, ushort* __restrict__ wf) {
    const float* W = p.w[blockIdx.x];
    ushort* o = wf + (size_t)blockIdx.x * 16384;
    for (int i = threadIdx.x; i < 16384; i += 256) {
        int j = i & 7, lane = (i >> 3) & 63, kc = (i >> 9) & 3, ct = i >> 11;
        int k = kc * 32 + (lane >> 4) * 8 + j;
        int n = ct * 16 + (lane & 15);
        o[i] = f2bf(W[k * HD + n]);
    }
}

// ---------------- aggregation (bf16 rows, fp32 accumulate) ----------------

__global__ __launch_bounds__(256) void aggregate_kernel(
    const ushort* __restrict__ h, const int* __restrict__ rowp,
    const int* __restrict__ colv, ushort* __restrict__ outv, int n) {
    int node = blockIdx.x * 16 + (threadIdx.x >> 4);
    int l = threadIdx.x & 15;  // 16 lanes/node, 16B each
    if (node >= n) return;
    int beg = rowp[node], end = rowp[node + 1];
    const uint4* hp = (const uint4*)h;
    float a[8];
    uint4 sv = hp[(size_t)node * 16 + l];
    unpack8(sv, a);
    for (int j = beg; j < end; ++j) {
        uint4 v = hp[(size_t)colv[j] * 16 + l];
        float b[8];
        unpack8(v, b);
#pragma unroll
        for (int i = 0; i < 8; ++i) a[i] += b[i];
    }
    ((uint4*)outv)[(size_t)node * 16 + l] = pack8(a);
}

// ---------------- MFMA GEMM: [N,128](bf16) @ [128,128](bf16 frags) + bias ----------
// 3125 blocks x 256 threads (4 waves). Block = one 16-row tile; wave w owns
// col-tiles ct = {2w, 2w+1}. B-frags in registers (8 uint4/lane), A direct from
// global (4 uint4/lane), all loads independent -> 48 waves/CU offered for TLP.
// C coalesced via 4KB LDS tile. STATS: 1 atomic/thread, 32-way split.
// PRE_BN: scale/shift (128 floats each) precomputed by finalize kernel.

template <bool STATS, bool PRE_BN, bool READOUT>
__global__ __launch_bounds__(256, 4) void mfma_gemm_kernel(
    const ushort* __restrict__ A, const ushort* __restrict__ Wf,
    const float* __restrict__ bias, ushort* __restrict__ out,
    const float* __restrict__ sca, const float* __restrict__ shf,
    float* __restrict__ ssum_p, float* __restrict__ ssq_p,
    const int* __restrict__ gptr, float* __restrict__ gout) {
    __shared__ ushort cbuf[16 * HD];   // 4 KB C tile
    __shared__ float reds[HD];
    __shared__ float redq[HD];
    const int t = threadIdx.x;
    const int wave = t >> 6, lane = t & 63;
    const int quad = lane >> 4, l16 = lane & 15;
    const int row0 = blockIdx.x * 16;
    const int rowA = row0 + l16;       // always valid: 50000 = 3125*16

    // B-frags for this wave's two col-tiles (registers, independent loads)
    const uint4* Wf4 = (const uint4*)Wf;
    uint4 bfr[2][4];
#pragma unroll
    for (int c = 0; c < 2; ++c)
#pragma unroll
        for (int kc = 0; kc < 4; ++kc)
            bfr[c][kc] = Wf4[((2 * wave + c) * 4 + kc) * 64 + lane];

    // A-frags direct from global
    U16 afr[4];
    {
        const ushort* ap = A + (size_t)rowA * HD + quad * 8;
#pragma unroll
        for (int kc = 0; kc < 4; ++kc)
            afr[kc].u = *(const uint4*)(ap + kc * 32);
    }
    if (PRE_BN) {
#pragma unroll
        for (int kc = 0; kc < 4; ++kc) {
            float f[8];
            unpack8(afr[kc].u, f);
            int kb = kc * 32 + quad * 8;
            float4 s0 = ((const float4*)(sca + kb))[0];
            float4 s1 = ((const float4*)(sca + kb))[1];
            float4 h0 = ((const float4*)(shf + kb))[0];
            float4 h1 = ((const float4*)(shf + kb))[1];
            f[0] = fmaxf(fmaf(f[0], s0.x, h0.x), 0.f);
            f[1] = fmaxf(fmaf(f[1], s0.y, h0.y), 0.f);
            f[2] = fmaxf(fmaf(f[2], s0.z, h0.z), 0.f);
            f[3] = fmaxf(fmaf(f[3], s0.w, h0.w), 0.f);
            f[4] = fmaxf(fmaf(f[4], s1.x, h1.x), 0.f);
            f[5] = fmaxf(fmaf(f[5], s1.y, h1.y), 0.f);
            f[6] = fmaxf(fmaf(f[6], s1.z, h1.z), 0.f);
            f[7] = fmaxf(fmaf(f[7], s1.w, h1.w), 0.f);
            afr[kc].u = pack8(f);
        }
    }

    floatx4 zf = {0.f, 0.f, 0.f, 0.f};
    floatx4 acc[2] = {zf, zf};
#pragma unroll
    for (int kc = 0; kc < 4; ++kc) {
#pragma unroll
        for (int c = 0; c < 2; ++c) {
            U16 bu;
            bu.u = bfr[c][kc];
            acc[c] = __builtin_amdgcn_mfma_f32_16x16x32_bf16(afr[kc].h, bu.h, acc[c], 0, 0, 0);
        }
    }

    // C/D layout: col = ct*16 + l16, row = row0 + quad*4 + reg
    if (READOUT) {
        int r_base = row0 + quad * 4;
        int lo = 0, hi = NG - 1;
        while (lo < hi) {
            int mid = (lo + hi) >> 1;
            if (r_base >= gptr[mid + 1]) lo = mid + 1; else hi = mid;
        }
        int segr[4];
        int sg = lo;
#pragma unroll
        for (int reg = 0; reg < 4; ++reg) {
            while (r_base + reg >= gptr[sg + 1]) ++sg;
            segr[reg] = sg;
        }
#pragma unroll
        for (int c = 0; c < 2; ++c) {
            int col = (2 * wave + c) * 16 + l16;
            float b = bias[col];
            float run = 0.f;
            int cur = segr[0];
#pragma unroll
            for (int reg = 0; reg < 4; ++reg) {
                if (segr[reg] != cur) {
                    if (run != 0.f) atomicAdd(&gout[cur * HD + col], run);
                    run = 0.f;
                    cur = segr[reg];
                }
                run += fmaxf(acc[c][reg] + b, 0.f);
            }
            if (run != 0.f) atomicAdd(&gout[cur * HD + col], run);
        }
        return;
    }

    const int lrow = quad * 4;
#pragma unroll
    for (int c = 0; c < 2; ++c) {
        int col = (2 * wave + c) * 16 + l16;
        float b = bias[col];
        float s = 0.f, q = 0.f;
#pragma unroll
        for (int reg = 0; reg < 4; ++reg) {
            float v = acc[c][reg] + b;
            if (!STATS) v = fmaxf(v, 0.f);   // GEMM-B: relu; GEMM-A: raw pre-BN
            cbuf[(lrow + reg) * HD + col] = f2bf(v);
            if (STATS) { s += v; q += v * v; }
        }
        if (STATS) {
            // fold over the 4 quads (rows 0..15) for this col
            s += __shfl_xor(s, 16); s += __shfl_xor(s, 32);
            q += __shfl_xor(q, 16); q += __shfl_xor(q, 32);
            if (quad == 0) { reds[col] = s; redq[col] = q; }  // col strips disjoint per wave
        }
    }
    __syncthreads();

    // coalesced C store: 256 threads x 1 uint4
    {
        const uint4* c4 = (const uint4*)cbuf;
        uint4* o4 = (uint4*)out;
        int row = t >> 4, part = t & 15;
        o4[(size_t)(row0 + row) * 16 + part] = c4[t];
    }

    if (STATS) {
        int slot = (blockIdx.x & (NSPLIT - 1)) * HD;
        if (t < HD) atomicAdd(&ssum_p[slot + t], reds[t]);
        else        atomicAdd(&ssq_p[slot + (t - HD)], redq[t - HD]);
    }
}

__global__ void finalize_stats_kernel(const float* __restrict__ sp, const float* __restrict__ qp,
                                      const float* __restrict__ gamma, const float* __restrict__ beta,
                                      float* __restrict__ sca, float* __restrict__ shf) {
    int c = threadIdx.x;
    float s = 0.f, q = 0.f;
#pragma unroll
    for (int i = 0; i < NSPLIT; ++i) { s += sp[i * HD + c]; q += qp[i * HD + c]; }
    float mean = s / (float)NNODES;
    float var = q / (float)NNODES - mean * mean;
    float rstd = rsqrtf(var + BN_EPS);
    float sc = gamma[c] * rstd;
    sca[c] = sc;
    shf[c] = beta[c] - mean * sc;
}

// ---------------- launch ----------------

extern "C" void kernel_launch(void* const* d_in, const int* in_sizes, int n_in,
                              void* d_out, int out_size, void* d_ws, size_t ws_size,
                              hipStream_t stream) {
    const float* x = (const float*)d_in[0];
    const int* esrc = (const int*)d_in[1];
    const int* edst = (const int*)d_in[2];
    const int* gptr = (const int*)d_in[3];
    const float* wA[3] = {(const float*)d_in[4], (const float*)d_in[10], (const float*)d_in[16]};
    const float* bA[3] = {(const float*)d_in[5], (const float*)d_in[11], (const float*)d_in[17]};
    const float* gm[3] = {(const float*)d_in[6], (const float*)d_in[12], (const float*)d_in[18]};
    const float* bt[3] = {(const float*)d_in[7], (const float*)d_in[13], (const float*)d_in[19]};
    const float* wB[3] = {(const float*)d_in[8], (const float*)d_in[14], (const float*)d_in[20]};
    const float* bB[3] = {(const float*)d_in[9], (const float*)d_in[15], (const float*)d_in[21]};

    char* w = (char*)d_ws;
    ushort* xb   = (ushort*)w; w += (size_t)NNODES * HD * 2;  // 12.8 MB
    ushort* tmpb = (ushort*)w; w += (size_t)NNODES * HD * 2;
    ushort* zbb  = (ushort*)w; w += (size_t)NNODES * HD * 2;
    ushort* hbb  = (ushort*)w; w += (size_t)NNODES * HD * 2;
    ushort* wf   = (ushort*)w; w += (size_t)6 * 16384 * 2;    // 192 KB
    int* colv  = (int*)w;   w += (size_t)NEDGES * 4;
    int* incl  = (int*)w;   w += (size_t)NNODES * 4;
    int* rowp  = (int*)w;   w += ((size_t)(NNODES + 1) * 4 + 15) & ~(size_t)15;
    int* bsum  = (int*)w;   w += 64 * 4;
    int* boffs = (int*)w;   w += 64 * 4;
    float* scab = (float*)w; w += 3 * 128 * 4;
    float* shfb = (float*)w; w += 3 * 128 * 4;
    // ---- zero region ----
    char* zero_base = w;
    int* cnt   = (int*)w;   w += (size_t)NNODES * 4;
    int* fill  = (int*)w;   w += (size_t)NNODES * 4;
    float* ssum_p = (float*)w; w += 3 * NSPLIT * 128 * 4;
    float* ssq_p  = (float*)w; w += 3 * NSPLIT * 128 * 4;
    size_t zero_bytes = (size_t)(w - zero_base);

    hipMemsetAsync(zero_base, 0, zero_bytes, stream);
    hipMemsetAsync(d_out, 0, (size_t)NG * HD * 4, stream);

    // CSR by destination
    hist_kernel<<<(NEDGES + 255) / 256, 256, 0, stream>>>(edst, cnt, NEDGES);
    int nsb = (NNODES + 1023) / 1024;  // 49
    scan1_kernel<<<nsb, 1024, 0, stream>>>(cnt, incl, bsum, NNODES);
    scan2_kernel<<<1, 64, 0, stream>>>(bsum, boffs, nsb);
    scan3_kernel<<<(NNODES + 255) / 256, 256, 0, stream>>>(incl, boffs, rowp, NNODES);
    build_kernel<<<(NEDGES + 255) / 256, 256, 0, stream>>>(esrc, edst, rowp, fill, colv, NEDGES);

    cvt_kernel<<<(NNODES * HD / 4 + 255) / 256, 256, 0, stream>>>(x, xb, NNODES * HD / 4);
    WP6 wp;
    wp.w[0] = wA[0]; wp.w[1] = wB[0]; wp.w[2] = wA[1];
    wp.w[3] = wB[1]; wp.w[4] = wA[2]; wp.w[5] = wB[2];
    wfrag_kernel<<<6, 256, 0, stream>>>(wp, wf);

    const int agg_grid = (NNODES + 15) / 16;   // 3125
    const ushort* hin = xb;
    for (int l = 0; l < 3; ++l) {
        aggregate_kernel<<<agg_grid, 256, 0, stream>>>(hin, rowp, colv, tmpb, NNODES);
        mfma_gemm_kernel<true, false, false><<<NTILE, 256, 0, stream>>>(
            tmpb, wf + (size_t)(2 * l) * 16384, bA[l], zbb, nullptr, nullptr,
            ssum_p + l * NSPLIT * 128, ssq_p + l * NSPLIT * 128, nullptr, nullptr);
        finalize_stats_kernel<<<1, 128, 0, stream>>>(
            ssum_p + l * NSPLIT * 128, ssq_p + l * NSPLIT * 128,
            gm[l], bt[l], scab + l * 128, shfb + l * 128);
        if (l < 2) {
            mfma_gemm_kernel<false, true, false><<<NTILE, 256, 0, stream>>>(
                zbb, wf + (size_t)(2 * l + 1) * 16384, bB[l], hbb,
                scab + l * 128, shfb + l * 128, nullptr, nullptr, nullptr, nullptr);
        } else {
            mfma_gemm_kernel<false, true, true><<<NTILE, 256, 0, stream>>>(
                zbb, wf + (size_t)(2 * l + 1) * 16384, bB[l], nullptr,
                scab + l * 128, shfb + l * 128, nullptr, nullptr,
                gptr, (float*)d_out);
        }
        hin = hbb;
    }
}

// Round 11
// 422.020 us; speedup vs baseline: 1.1829x; 1.0862x over previous
//
#include <hip/hip_runtime.h>

#define NNODES 50000
#define NEDGES 800000
#define HD 128
#define NG 512
#define BN_EPS 1e-5f
#define NTILE 3125           // 16-row tiles: 50000 = 3125 * 16 exactly
#define NSPLIT 8             // stats atomic split
#define NSB 49               // scan blocks (50000 / 1024 rounded up)
#define AROW 136             // padded A-tile row in ushorts (272 B)

typedef short bf16x8 __attribute__((ext_vector_type(8)));
typedef float floatx4 __attribute__((ext_vector_type(4)));

union U16 { uint4 u; bf16x8 h; };

__device__ __forceinline__ ushort f2bf(float f) {
    unsigned u = __float_as_uint(f);
    return (ushort)((u + 0x7fffu + ((u >> 16) & 1u)) >> 16);
}
__device__ __forceinline__ void unpack8(const uint4& u, float* f) {
    const unsigned* w = (const unsigned*)&u;
#pragma unroll
    for (int i = 0; i < 4; ++i) {
        f[2 * i]     = __uint_as_float(w[i] << 16);
        f[2 * i + 1] = __uint_as_float(w[i] & 0xffff0000u);
    }
}
__device__ __forceinline__ uint4 pack8(const float* f) {
    uint4 o;
    unsigned* w = (unsigned*)&o;
#pragma unroll
    for (int i = 0; i < 4; ++i)
        w[i] = (unsigned)f2bf(f[2 * i]) | ((unsigned)f2bf(f[2 * i + 1]) << 16);
    return o;
}

// ---------------- prep: hist + fp32->bf16 cvt + weight-frag pack, one dispatch ----
// blocks [0,3125): histogram of edge dst
// blocks [3125, 9375): cvt x -> xb (float4 granularity)
// blocks [9375, 9381): pack 6 weight matrices into MFMA B-frag order

struct WP6 { const float* w[6]; };

__global__ __launch_bounds__(256) void prep_kernel(
    const int* __restrict__ edst, int* __restrict__ cnt,
    const float* __restrict__ x, ushort* __restrict__ xb,
    WP6 p, ushort* __restrict__ wf) {
    const int b = blockIdx.x, t = threadIdx.x;
    if (b < 3125) {
        atomicAdd(&cnt[edst[b * 256 + t]], 1);
    } else if (b < 9375) {
        int i = (b - 3125) * 256 + t;
        float4 v = ((const float4*)x)[i];
        ushort4 o;
        o.x = f2bf(v.x); o.y = f2bf(v.y); o.z = f2bf(v.z); o.w = f2bf(v.w);
        ((ushort4*)xb)[i] = o;
    } else {
        int m = b - 9375;
        const float* W = p.w[m];
        ushort* o = wf + (size_t)m * 16384;
        for (int i = t; i < 16384; i += 256) {
            int j = i & 7, lane = (i >> 3) & 63, kc = (i >> 9) & 3, ct = i >> 11;
            int k = kc * 32 + (lane >> 4) * 8 + j;
            int n = ct * 16 + (lane & 15);
            o[i] = f2bf(W[k * HD + n]);
        }
    }
}

// ---------------- CSR scan ----------------

__global__ void scan1_kernel(const int* __restrict__ cnt, int* __restrict__ incl,
                             int* __restrict__ bsum, int n) {
    __shared__ int s[1024];
    int i = blockIdx.x * 1024 + threadIdx.x;
    int v = (i < n) ? cnt[i] : 0;
    s[threadIdx.x] = v;
    __syncthreads();
    for (int off = 1; off < 1024; off <<= 1) {
        int add = (threadIdx.x >= off) ? s[threadIdx.x - off] : 0;
        __syncthreads();
        s[threadIdx.x] += add;
        __syncthreads();
    }
    if (i < n) incl[i] = s[threadIdx.x];
    if (threadIdx.x == 1023) bsum[blockIdx.x] = s[1023];
}

// scan2+scan3 merged: every block re-derives the 49-element exclusive prefix
__global__ void scan23_kernel(const int* __restrict__ incl, const int* __restrict__ bsum,
                              int* __restrict__ rowp, int n) {
    __shared__ int bpre[64];
    const int t = threadIdx.x;
    if (t < 64) {
        int own = (t < NSB) ? bsum[t] : 0;
        int v = own;
        for (int off = 1; off < 64; off <<= 1) {
            int u = __shfl_up(v, off);
            if (t >= off) v += u;
        }
        bpre[t] = v - own;  // exclusive prefix
    }
    __syncthreads();
    int i = blockIdx.x * 256 + t;
    if (i < n) rowp[i + 1] = incl[i] + bpre[i >> 10];
    if (i == 0) rowp[0] = 0;
}

__global__ void build_kernel(const int* __restrict__ src, const int* __restrict__ dst,
                             const int* __restrict__ rowp, int* __restrict__ fill,
                             int* __restrict__ colv, int n) {
    int i = blockIdx.x * 256 + threadIdx.x;
    if (i < n) {
        int d = dst[i];
        int pos = rowp[d] + atomicAdd(&fill[d], 1);
        colv[pos] = src[i];
    }
}

// ---------------- fused gather + GEMM-A + stats --------------------------------
// 3125 blocks x 256 threads (4 waves), one 16-row tile per block.
// Gather phase uses the proven fast shape: 16 lanes/row x 16B, fp32 accumulate,
// writing a padded LDS A-tile. B-frags prefetched into registers BEFORE the
// gather so their latency overlaps it. After one barrier: MFMA from LDS A.
// z (pre-BN) stored coalesced via LDS; stats via wave-fold + NSPLIT atomics.

__global__ __launch_bounds__(256, 4) void gemmA_kernel(
    const ushort* __restrict__ H, const int* __restrict__ rowp,
    const int* __restrict__ colv, const ushort* __restrict__ Wf,
    const float* __restrict__ bias, ushort* __restrict__ out,
    float* __restrict__ ssum_p, float* __restrict__ ssq_p) {
    __shared__ ushort abuf[16 * AROW];   // 4.25 KB padded A tile
    __shared__ ushort cbuf[16 * HD];     // 4 KB z tile
    __shared__ float reds[HD];
    __shared__ float redq[HD];
    const int t = threadIdx.x;
    const int wave = t >> 6, lane = t & 63;
    const int quad = lane >> 4, l16 = lane & 15;
    const int row0 = blockIdx.x * 16;

    // B-frags first (independent; latency hides under the gather)
    const uint4* Wf4 = (const uint4*)Wf;
    uint4 bfr[2][4];
#pragma unroll
    for (int c = 0; c < 2; ++c)
#pragma unroll
        for (int kc = 0; kc < 4; ++kc)
            bfr[c][kc] = Wf4[((2 * wave + c) * 4 + kc) * 64 + lane];

    // gather: node = row0 + (t>>4), 16B chunk l = t&15
    {
        int nl = t >> 4;
        int node = row0 + nl;
        int l = t & 15;
        int beg = rowp[node], end = rowp[node + 1];
        const uint4* hp = (const uint4*)H;
        float a[8];
        unpack8(hp[(size_t)node * 16 + l], a);
        for (int j = beg; j < end; ++j) {
            float b[8];
            unpack8(hp[(size_t)colv[j] * 16 + l], b);
#pragma unroll
            for (int i = 0; i < 8; ++i) a[i] += b[i];
        }
        *(uint4*)&abuf[nl * AROW + l * 8] = pack8(a);
    }
    __syncthreads();

    // A-frags from LDS (row = l16, padded stride avoids heavy conflicts)
    U16 afr[4];
#pragma unroll
    for (int kc = 0; kc < 4; ++kc)
        afr[kc].u = *(const uint4*)&abuf[l16 * AROW + kc * 32 + quad * 8];

    floatx4 zf = {0.f, 0.f, 0.f, 0.f};
    floatx4 acc[2] = {zf, zf};
#pragma unroll
    for (int kc = 0; kc < 4; ++kc) {
#pragma unroll
        for (int c = 0; c < 2; ++c) {
            U16 bu;
            bu.u = bfr[c][kc];
            acc[c] = __builtin_amdgcn_mfma_f32_16x16x32_bf16(afr[kc].h, bu.h, acc[c], 0, 0, 0);
        }
    }

    // epilogue: raw z -> cbuf + per-col stats
    const int lrow = quad * 4;
#pragma unroll
    for (int c = 0; c < 2; ++c) {
        int col = (2 * wave + c) * 16 + l16;
        float b = bias[col];
        float s = 0.f, q = 0.f;
#pragma unroll
        for (int reg = 0; reg < 4; ++reg) {
            float v = acc[c][reg] + b;
            cbuf[(lrow + reg) * HD + col] = f2bf(v);
            s += v; q += v * v;
        }
        s += __shfl_xor(s, 16); s += __shfl_xor(s, 32);
        q += __shfl_xor(q, 16); q += __shfl_xor(q, 32);
        if (quad == 0) { reds[col] = s; redq[col] = q; }
    }
    __syncthreads();

    // coalesced z store
    {
        const uint4* c4 = (const uint4*)cbuf;
        uint4* o4 = (uint4*)out;
        int row = t >> 4, part = t & 15;
        o4[(size_t)(row0 + row) * 16 + part] = c4[t];
    }

    int slot = (blockIdx.x & (NSPLIT - 1)) * HD;
    if (t < HD) atomicAdd(&ssum_p[slot + t], reds[t]);
    else        atomicAdd(&ssq_p[slot + (t - HD)], redq[t - HD]);
}

// ---------------- GEMM-B: inline BN finalize + BN/relu + GEMM (+readout) -------

template <bool READOUT>
__global__ __launch_bounds__(256, 4) void gemmB_kernel(
    const ushort* __restrict__ A, const ushort* __restrict__ Wf,
    const float* __restrict__ bias, ushort* __restrict__ out,
    const float* __restrict__ gamma, const float* __restrict__ beta,
    const float* __restrict__ ssum_p, const float* __restrict__ ssq_p,
    const int* __restrict__ gptr, float* __restrict__ gout) {
    __shared__ ushort cbuf[16 * HD];
    __shared__ float sca[HD];
    __shared__ float shf[HD];
    const int t = threadIdx.x;
    const int wave = t >> 6, lane = t & 63;
    const int quad = lane >> 4, l16 = lane & 15;
    const int row0 = blockIdx.x * 16;
    const int rowA = row0 + l16;

    // B-frags (registers)
    const uint4* Wf4 = (const uint4*)Wf;
    uint4 bfr[2][4];
#pragma unroll
    for (int c = 0; c < 2; ++c)
#pragma unroll
        for (int kc = 0; kc < 4; ++kc)
            bfr[c][kc] = Wf4[((2 * wave + c) * 4 + kc) * 64 + lane];

    // A-frags direct from global
    U16 afr[4];
    {
        const ushort* ap = A + (size_t)rowA * HD + quad * 8;
#pragma unroll
        for (int kc = 0; kc < 4; ++kc)
            afr[kc].u = *(const uint4*)(ap + kc * 32);
    }

    // inline BN finalize from split stats (stream-ordered complete)
    if (t < HD) {
        float s = 0.f, q = 0.f;
#pragma unroll
        for (int i = 0; i < NSPLIT; ++i) { s += ssum_p[i * HD + t]; q += ssq_p[i * HD + t]; }
        float mean = s / (float)NNODES;
        float var = q / (float)NNODES - mean * mean;
        float rstd = rsqrtf(var + BN_EPS);
        float sc = gamma[t] * rstd;
        sca[t] = sc;
        shf[t] = beta[t] - mean * sc;
    }
    __syncthreads();

    // BN + relu in registers
#pragma unroll
    for (int kc = 0; kc < 4; ++kc) {
        float f[8];
        unpack8(afr[kc].u, f);
        int kb = kc * 32 + quad * 8;
        float4 s0 = ((const float4*)(sca + kb))[0];
        float4 s1 = ((const float4*)(sca + kb))[1];
        float4 h0 = ((const float4*)(shf + kb))[0];
        float4 h1 = ((const float4*)(shf + kb))[1];
        f[0] = fmaxf(fmaf(f[0], s0.x, h0.x), 0.f);
        f[1] = fmaxf(fmaf(f[1], s0.y, h0.y), 0.f);
        f[2] = fmaxf(fmaf(f[2], s0.z, h0.z), 0.f);
        f[3] = fmaxf(fmaf(f[3], s0.w, h0.w), 0.f);
        f[4] = fmaxf(fmaf(f[4], s1.x, h1.x), 0.f);
        f[5] = fmaxf(fmaf(f[5], s1.y, h1.y), 0.f);
        f[6] = fmaxf(fmaf(f[6], s1.z, h1.z), 0.f);
        f[7] = fmaxf(fmaf(f[7], s1.w, h1.w), 0.f);
        afr[kc].u = pack8(f);
    }

    floatx4 zf = {0.f, 0.f, 0.f, 0.f};
    floatx4 acc[2] = {zf, zf};
#pragma unroll
    for (int kc = 0; kc < 4; ++kc) {
#pragma unroll
        for (int c = 0; c < 2; ++c) {
            U16 bu;
            bu.u = bfr[c][kc];
            acc[c] = __builtin_amdgcn_mfma_f32_16x16x32_bf16(afr[kc].h, bu.h, acc[c], 0, 0, 0);
        }
    }

    if (READOUT) {
        int r_base = row0 + quad * 4;
        int lo = 0, hi = NG - 1;
        while (lo < hi) {
            int mid = (lo + hi) >> 1;
            if (r_base >= gptr[mid + 1]) lo = mid + 1; else hi = mid;
        }
        int segr[4];
        int sg = lo;
#pragma unroll
        for (int reg = 0; reg < 4; ++reg) {
            while (r_base + reg >= gptr[sg + 1]) ++sg;
            segr[reg] = sg;
        }
#pragma unroll
        for (int c = 0; c < 2; ++c) {
            int col = (2 * wave + c) * 16 + l16;
            float b = bias[col];
            float run = 0.f;
            int cur = segr[0];
#pragma unroll
            for (int reg = 0; reg < 4; ++reg) {
                if (segr[reg] != cur) {
                    if (run != 0.f) atomicAdd(&gout[cur * HD + col], run);
                    run = 0.f;
                    cur = segr[reg];
                }
                run += fmaxf(acc[c][reg] + b, 0.f);
            }
            if (run != 0.f) atomicAdd(&gout[cur * HD + col], run);
        }
        return;
    }

    const int lrow = quad * 4;
#pragma unroll
    for (int c = 0; c < 2; ++c) {
        int col = (2 * wave + c) * 16 + l16;
        float b = bias[col];
#pragma unroll
        for (int reg = 0; reg < 4; ++reg)
            cbuf[(lrow + reg) * HD + col] = f2bf(fmaxf(acc[c][reg] + b, 0.f));
    }
    __syncthreads();
    {
        const uint4* c4 = (const uint4*)cbuf;
        uint4* o4 = (uint4*)out;
        int row = t >> 4, part = t & 15;
        o4[(size_t)(row0 + row) * 16 + part] = c4[t];
    }
}

// ---------------- launch ----------------

extern "C" void kernel_launch(void* const* d_in, const int* in_sizes, int n_in,
                              void* d_out, int out_size, void* d_ws, size_t ws_size,
                              hipStream_t stream) {
    const float* x = (const float*)d_in[0];
    const int* esrc = (const int*)d_in[1];
    const int* edst = (const int*)d_in[2];
    const int* gptr = (const int*)d_in[3];
    const float* wA[3] = {(const float*)d_in[4], (const float*)d_in[10], (const float*)d_in[16]};
    const float* bA[3] = {(const float*)d_in[5], (const float*)d_in[11], (const float*)d_in[17]};
    const float* gm[3] = {(const float*)d_in[6], (const float*)d_in[12], (const float*)d_in[18]};
    const float* bt[3] = {(const float*)d_in[7], (const float*)d_in[13], (const float*)d_in[19]};
    const float* wB[3] = {(const float*)d_in[8], (const float*)d_in[14], (const float*)d_in[20]};
    const float* bB[3] = {(const float*)d_in[9], (const float*)d_in[15], (const float*)d_in[21]};

    char* w = (char*)d_ws;
    ushort* xb   = (ushort*)w; w += (size_t)NNODES * HD * 2;  // 12.8 MB
    ushort* zbb  = (ushort*)w; w += (size_t)NNODES * HD * 2;
    ushort* hbb  = (ushort*)w; w += (size_t)NNODES * HD * 2;
    ushort* wf   = (ushort*)w; w += (size_t)6 * 16384 * 2;    // 192 KB
    int* colv  = (int*)w;   w += (size_t)NEDGES * 4;
    int* incl  = (int*)w;   w += (size_t)NNODES * 4;
    int* rowp  = (int*)w;   w += ((size_t)(NNODES + 1) * 4 + 15) & ~(size_t)15;
    int* bsum  = (int*)w;   w += 64 * 4;
    // ---- zero region ----
    char* zero_base = w;
    int* cnt   = (int*)w;   w += (size_t)NNODES * 4;
    int* fill  = (int*)w;   w += (size_t)NNODES * 4;
    float* ssum_p = (float*)w; w += 3 * NSPLIT * 128 * 4;
    float* ssq_p  = (float*)w; w += 3 * NSPLIT * 128 * 4;
    size_t zero_bytes = (size_t)(w - zero_base);

    hipMemsetAsync(zero_base, 0, zero_bytes, stream);
    hipMemsetAsync(d_out, 0, (size_t)NG * HD * 4, stream);

    WP6 wp;
    wp.w[0] = wA[0]; wp.w[1] = wB[0]; wp.w[2] = wA[1];
    wp.w[3] = wB[1]; wp.w[4] = wA[2]; wp.w[5] = wB[2];

    // prep: hist + cvt + wfrag (one dispatch)
    prep_kernel<<<9381, 256, 0, stream>>>(edst, cnt, x, xb, wp, wf);
    scan1_kernel<<<NSB, 1024, 0, stream>>>(cnt, incl, bsum, NNODES);
    scan23_kernel<<<(NNODES + 255) / 256, 256, 0, stream>>>(incl, bsum, rowp, NNODES);
    build_kernel<<<(NEDGES + 255) / 256, 256, 0, stream>>>(esrc, edst, rowp, fill, colv, NEDGES);

    const ushort* hin = xb;
    for (int l = 0; l < 3; ++l) {
        gemmA_kernel<<<NTILE, 256, 0, stream>>>(
            hin, rowp, colv, wf + (size_t)(2 * l) * 16384, bA[l], zbb,
            ssum_p + l * NSPLIT * 128, ssq_p + l * NSPLIT * 128);
        if (l < 2) {
            gemmB_kernel<false><<<NTILE, 256, 0, stream>>>(
                zbb, wf + (size_t)(2 * l + 1) * 16384, bB[l], hbb, gm[l], bt[l],
                ssum_p + l * NSPLIT * 128, ssq_p + l * NSPLIT * 128, nullptr, nullptr);
        } else {
            gemmB_kernel<true><<<NTILE, 256, 0, stream>>>(
                zbb, wf + (size_t)(2 * l + 1) * 16384, bB[l], nullptr, gm[l], bt[l],
                ssum_p + l * NSPLIT * 128, ssq_p + l * NSPLIT * 128, gptr, (float*)d_out);
        }
        hin = hbb;
    }
}

// Round 12
// 402.873 us; speedup vs baseline: 1.2392x; 1.0475x over previous
//
#include <hip/hip_runtime.h>

#define NNODES 50000
#define NEDGES 800000
#define HD 128
#define NG 512
#define BN_EPS 1e-5f
#define NTILE 3125           // 16-row tiles: 50000 = 3125 * 16 exactly
#define NSPLIT 8             // stats atomic split
#define NSB 49               // scan blocks
#define AROW 136             // padded LDS tile row in ushorts (272 B)

typedef short bf16x8 __attribute__((ext_vector_type(8)));
typedef float floatx4 __attribute__((ext_vector_type(4)));

union U16 { uint4 u; bf16x8 h; };

__device__ __forceinline__ ushort f2bf(float f) {
    unsigned u = __float_as_uint(f);
    return (ushort)((u + 0x7fffu + ((u >> 16) & 1u)) >> 16);
}
__device__ __forceinline__ void unpack8(const uint4& u, float* f) {
    const unsigned* w = (const unsigned*)&u;
#pragma unroll
    for (int i = 0; i < 4; ++i) {
        f[2 * i]     = __uint_as_float(w[i] << 16);
        f[2 * i + 1] = __uint_as_float(w[i] & 0xffff0000u);
    }
}
__device__ __forceinline__ uint4 pack8(const float* f) {
    uint4 o;
    unsigned* w = (unsigned*)&o;
#pragma unroll
    for (int i = 0; i < 4; ++i)
        w[i] = (unsigned)f2bf(f[2 * i]) | ((unsigned)f2bf(f[2 * i + 1]) << 16);
    return o;
}

// ---------------- prep: hist(+rank) + weight-frag pack, one dispatch ------------

struct WP6 { const float* w[6]; };

__global__ __launch_bounds__(256) void prep_kernel(
    const int* __restrict__ edst, int* __restrict__ cnt, int* __restrict__ rank,
    WP6 p, ushort* __restrict__ wf) {
    const int b = blockIdx.x, t = threadIdx.x;
    if (b < 3125) {
        int i = b * 256 + t;
        rank[i] = atomicAdd(&cnt[edst[i]], 1);
    } else {
        int m = b - 3125;
        const float* W = p.w[m];
        ushort* o = wf + (size_t)m * 16384;
        for (int i = t; i < 16384; i += 256) {
            int j = i & 7, lane = (i >> 3) & 63, kc = (i >> 9) & 3, ct = i >> 11;
            int k = kc * 32 + (lane >> 4) * 8 + j;
            int n = ct * 16 + (lane & 15);
            o[i] = f2bf(W[k * HD + n]);
        }
    }
}

// ---------------- CSR scan ----------------

__global__ void scan1_kernel(const int* __restrict__ cnt, int* __restrict__ incl,
                             int* __restrict__ bsum, int n) {
    __shared__ int s[1024];
    int i = blockIdx.x * 1024 + threadIdx.x;
    int v = (i < n) ? cnt[i] : 0;
    s[threadIdx.x] = v;
    __syncthreads();
    for (int off = 1; off < 1024; off <<= 1) {
        int add = (threadIdx.x >= off) ? s[threadIdx.x - off] : 0;
        __syncthreads();
        s[threadIdx.x] += add;
        __syncthreads();
    }
    if (i < n) incl[i] = s[threadIdx.x];
    if (threadIdx.x == 1023) bsum[blockIdx.x] = s[1023];
}

__global__ void scan23_kernel(const int* __restrict__ incl, const int* __restrict__ bsum,
                              int* __restrict__ rowp, int n) {
    __shared__ int bpre[64];
    const int t = threadIdx.x;
    if (t < 64) {
        int own = (t < NSB) ? bsum[t] : 0;
        int v = own;
        for (int off = 1; off < 64; off <<= 1) {
            int u = __shfl_up(v, off);
            if (t >= off) v += u;
        }
        bpre[t] = v - own;  // exclusive prefix
    }
    __syncthreads();
    int i = blockIdx.x * 256 + t;
    if (i < n) rowp[i + 1] = incl[i] + bpre[i >> 10];
    if (i == 0) rowp[0] = 0;
}

// build: no atomics — rank precomputed in prep
__global__ void build_kernel(const int* __restrict__ src, const int* __restrict__ dst,
                             const int* __restrict__ rowp, const int* __restrict__ rank,
                             int* __restrict__ colv, int n) {
    int i = blockIdx.x * 256 + threadIdx.x;
    if (i < n) colv[rowp[dst[i]] + rank[i]] = src[i];
}

// ---------------- gemm0A: y0 = x(fp32) @ Wa0, no bias --------------------------
// coalesced fp32 tile load -> LDS bf16 (padded) -> A-frags -> MFMA -> y0

__global__ __launch_bounds__(256, 4) void gemm0A_kernel(
    const float* __restrict__ x, const ushort* __restrict__ Wf,
    ushort* __restrict__ y) {
    __shared__ ushort abuf[16 * AROW];
    __shared__ ushort cbuf[16 * HD];
    const int t = threadIdx.x;
    const int wave = t >> 6, lane = t & 63;
    const int quad = lane >> 4, l16 = lane & 15;
    const int row0 = blockIdx.x * 16;

    // B-frags to registers
    const uint4* Wf4 = (const uint4*)Wf;
    uint4 bfr[2][4];
#pragma unroll
    for (int c = 0; c < 2; ++c)
#pragma unroll
        for (int kc = 0; kc < 4; ++kc)
            bfr[c][kc] = Wf4[((2 * wave + c) * 4 + kc) * 64 + lane];

    // coalesced x tile: thread t -> row t>>4, floats (t&15)*8 .. +8
    {
        int r = t >> 4, l = t & 15;
        const float* xp = x + (size_t)(row0 + r) * HD + l * 8;
        float4 v0 = ((const float4*)xp)[0];
        float4 v1 = ((const float4*)xp)[1];
        float f[8] = {v0.x, v0.y, v0.z, v0.w, v1.x, v1.y, v1.z, v1.w};
        *(uint4*)&abuf[r * AROW + l * 8] = pack8(f);
    }
    __syncthreads();

    U16 afr[4];
#pragma unroll
    for (int kc = 0; kc < 4; ++kc)
        afr[kc].u = *(const uint4*)&abuf[l16 * AROW + kc * 32 + quad * 8];

    floatx4 zf = {0.f, 0.f, 0.f, 0.f};
    floatx4 acc[2] = {zf, zf};
#pragma unroll
    for (int kc = 0; kc < 4; ++kc)
#pragma unroll
        for (int c = 0; c < 2; ++c) {
            U16 bu; bu.u = bfr[c][kc];
            acc[c] = __builtin_amdgcn_mfma_f32_16x16x32_bf16(afr[kc].h, bu.h, acc[c], 0, 0, 0);
        }

    const int lrow = quad * 4;
#pragma unroll
    for (int c = 0; c < 2; ++c) {
        int col = (2 * wave + c) * 16 + l16;
#pragma unroll
        for (int reg = 0; reg < 4; ++reg)
            cbuf[(lrow + reg) * HD + col] = f2bf(acc[c][reg]);
    }
    __syncthreads();
    {
        const uint4* c4 = (const uint4*)cbuf;
        uint4* o4 = (uint4*)y;
        int row = t >> 4, part = t & 15;
        o4[(size_t)(row0 + row) * 16 + part] = c4[t];
    }
}

// ---------------- agg: z = y + sum_nbr y + bias; stats of z --------------------

__global__ __launch_bounds__(256) void agg_kernel(
    const ushort* __restrict__ y, const int* __restrict__ rowp,
    const int* __restrict__ colv, const float* __restrict__ bias,
    ushort* __restrict__ z, float* __restrict__ ssum_p, float* __restrict__ ssq_p) {
    __shared__ float reds[4][HD];
    __shared__ float redq[4][HD];
    const int t = threadIdx.x;
    const int wave = t >> 6, lane = t & 63;
    const int node = blockIdx.x * 16 + (t >> 4);
    const int l = t & 15;
    const uint4* hp = (const uint4*)y;

    float a[8];
    unpack8(hp[(size_t)node * 16 + l], a);
    int beg = rowp[node], end = rowp[node + 1];
    for (int j = beg; j < end; ++j) {
        float b[8];
        unpack8(hp[(size_t)colv[j] * 16 + l], b);
#pragma unroll
        for (int i = 0; i < 8; ++i) a[i] += b[i];
    }
    {
        float4 b0 = ((const float4*)(bias + l * 8))[0];
        float4 b1 = ((const float4*)(bias + l * 8))[1];
        a[0] += b0.x; a[1] += b0.y; a[2] += b0.z; a[3] += b0.w;
        a[4] += b1.x; a[5] += b1.y; a[6] += b1.z; a[7] += b1.w;
    }
    ((uint4*)z)[(size_t)node * 16 + l] = pack8(a);

    // stats: fold the 4 nodes within this wave sharing chunk l
    float s[8], q[8];
#pragma unroll
    for (int i = 0; i < 8; ++i) { s[i] = a[i]; q[i] = a[i] * a[i]; }
#pragma unroll
    for (int i = 0; i < 8; ++i) {
        s[i] += __shfl_xor(s[i], 16); s[i] += __shfl_xor(s[i], 32);
        q[i] += __shfl_xor(q[i], 16); q[i] += __shfl_xor(q[i], 32);
    }
    if (lane < 16) {
#pragma unroll
        for (int i = 0; i < 8; ++i) {
            reds[wave][lane * 8 + i] = s[i];
            redq[wave][lane * 8 + i] = q[i];
        }
    }
    __syncthreads();
    int slot = (blockIdx.x & (NSPLIT - 1)) * HD;
    if (t < HD) {
        atomicAdd(&ssum_p[slot + t], reds[0][t] + reds[1][t] + reds[2][t] + reds[3][t]);
    } else if (t < 2 * HD) {
        int c = t - HD;
        atomicAdd(&ssq_p[slot + c], redq[0][c] + redq[1][c] + redq[2][c] + redq[3][c]);
    }
}

// ---------------- gemmBA: BN+relu -> @Wb +bb relu -> @Wa' -> y' ----------------
// h' stays in LDS only. Wb-frags in registers; Wa'-frags staged in LDS.

__global__ __launch_bounds__(256, 3) void gemmBA_kernel(
    const ushort* __restrict__ z, const ushort* __restrict__ WfB,
    const ushort* __restrict__ WfA2, const float* __restrict__ biasB,
    ushort* __restrict__ yout,
    const float* __restrict__ gamma, const float* __restrict__ beta,
    const float* __restrict__ ssum_p, const float* __restrict__ ssq_p) {
    __shared__ ushort was[16384];     // 32 KB Wa' frags
    __shared__ ushort cbuf[16 * AROW];
    __shared__ float sca[HD];
    __shared__ float shf[HD];
    const int t = threadIdx.x;
    const int wave = t >> 6, lane = t & 63;
    const int quad = lane >> 4, l16 = lane & 15;
    const int row0 = blockIdx.x * 16;
    const int rowA = row0 + l16;

    // stage Wa' into LDS (independent; overlaps everything below)
    {
        const uint4* g = (const uint4*)WfA2;
        uint4 v[8];
#pragma unroll
        for (int i = 0; i < 8; ++i) v[i] = g[i * 256 + t];
        uint4* s = (uint4*)was;
#pragma unroll
        for (int i = 0; i < 8; ++i) s[i * 256 + t] = v[i];
    }

    // Wb frags to registers
    const uint4* Wf4 = (const uint4*)WfB;
    uint4 bfr[2][4];
#pragma unroll
    for (int c = 0; c < 2; ++c)
#pragma unroll
        for (int kc = 0; kc < 4; ++kc)
            bfr[c][kc] = Wf4[((2 * wave + c) * 4 + kc) * 64 + lane];

    // z A-frags direct from global
    U16 afr[4];
    {
        const ushort* ap = z + (size_t)rowA * HD + quad * 8;
#pragma unroll
        for (int kc = 0; kc < 4; ++kc)
            afr[kc].u = *(const uint4*)(ap + kc * 32);
    }

    // BN finalize
    if (t < HD) {
        float s = 0.f, q = 0.f;
#pragma unroll
        for (int i = 0; i < NSPLIT; ++i) { s += ssum_p[i * HD + t]; q += ssq_p[i * HD + t]; }
        float mean = s / (float)NNODES;
        float var = q / (float)NNODES - mean * mean;
        float rstd = rsqrtf(var + BN_EPS);
        float sc = gamma[t] * rstd;
        sca[t] = sc;
        shf[t] = beta[t] - mean * sc;
    }
    __syncthreads();

    // BN + relu on A
#pragma unroll
    for (int kc = 0; kc < 4; ++kc) {
        float f[8];
        unpack8(afr[kc].u, f);
        int kb = kc * 32 + quad * 8;
        float4 s0 = ((const float4*)(sca + kb))[0];
        float4 s1 = ((const float4*)(sca + kb))[1];
        float4 h0 = ((const float4*)(shf + kb))[0];
        float4 h1 = ((const float4*)(shf + kb))[1];
        f[0] = fmaxf(fmaf(f[0], s0.x, h0.x), 0.f);
        f[1] = fmaxf(fmaf(f[1], s0.y, h0.y), 0.f);
        f[2] = fmaxf(fmaf(f[2], s0.z, h0.z), 0.f);
        f[3] = fmaxf(fmaf(f[3], s0.w, h0.w), 0.f);
        f[4] = fmaxf(fmaf(f[4], s1.x, h1.x), 0.f);
        f[5] = fmaxf(fmaf(f[5], s1.y, h1.y), 0.f);
        f[6] = fmaxf(fmaf(f[6], s1.z, h1.z), 0.f);
        f[7] = fmaxf(fmaf(f[7], s1.w, h1.w), 0.f);
        afr[kc].u = pack8(f);
    }

    floatx4 zf = {0.f, 0.f, 0.f, 0.f};
    floatx4 acc[2] = {zf, zf};
#pragma unroll
    for (int kc = 0; kc < 4; ++kc)
#pragma unroll
        for (int c = 0; c < 2; ++c) {
            U16 bu; bu.u = bfr[c][kc];
            acc[c] = __builtin_amdgcn_mfma_f32_16x16x32_bf16(afr[kc].h, bu.h, acc[c], 0, 0, 0);
        }

    // h' = relu(acc + bb) -> cbuf (A-layout source for second GEMM)
    const int lrow = quad * 4;
#pragma unroll
    for (int c = 0; c < 2; ++c) {
        int col = (2 * wave + c) * 16 + l16;
        float b = biasB[col];
#pragma unroll
        for (int reg = 0; reg < 4; ++reg)
            cbuf[(lrow + reg) * AROW + col] = f2bf(fmaxf(acc[c][reg] + b, 0.f));
    }
    __syncthreads();

    // second GEMM: A from cbuf, B from was (LDS)
    U16 a2[4];
#pragma unroll
    for (int kc = 0; kc < 4; ++kc)
        a2[kc].u = *(const uint4*)&cbuf[l16 * AROW + kc * 32 + quad * 8];
    const uint4* W2 = (const uint4*)was;
    floatx4 acc2[2] = {zf, zf};
#pragma unroll
    for (int kc = 0; kc < 4; ++kc)
#pragma unroll
        for (int c = 0; c < 2; ++c) {
            U16 bu; bu.u = W2[((2 * wave + c) * 4 + kc) * 64 + lane];
            acc2[c] = __builtin_amdgcn_mfma_f32_16x16x32_bf16(a2[kc].h, bu.h, acc2[c], 0, 0, 0);
        }
    __syncthreads();  // cbuf A-reads done

    // y' (raw, no bias/act) -> cbuf -> coalesced store
#pragma unroll
    for (int c = 0; c < 2; ++c) {
        int col = (2 * wave + c) * 16 + l16;
#pragma unroll
        for (int reg = 0; reg < 4; ++reg)
            cbuf[(lrow + reg) * AROW + col] = f2bf(acc2[c][reg]);
    }
    __syncthreads();
    {
        uint4* o4 = (uint4*)yout;
        int row = t >> 4, part = t & 15;
        o4[(size_t)(row0 + row) * 16 + part] = *(const uint4*)&cbuf[row * AROW + part * 8];
    }
}

// ---------------- gemmB2: BN+relu -> @Wb2 +bb2 relu -> segment readout ---------

__global__ __launch_bounds__(256, 4) void gemmB2_kernel(
    const ushort* __restrict__ z, const ushort* __restrict__ WfB,
    const float* __restrict__ biasB,
    const float* __restrict__ gamma, const float* __restrict__ beta,
    const float* __restrict__ ssum_p, const float* __restrict__ ssq_p,
    const int* __restrict__ gptr, float* __restrict__ gout) {
    __shared__ float sca[HD];
    __shared__ float shf[HD];
    const int t = threadIdx.x;
    const int wave = t >> 6, lane = t & 63;
    const int quad = lane >> 4, l16 = lane & 15;
    const int row0 = blockIdx.x * 16;
    const int rowA = row0 + l16;

    const uint4* Wf4 = (const uint4*)WfB;
    uint4 bfr[2][4];
#pragma unroll
    for (int c = 0; c < 2; ++c)
#pragma unroll
        for (int kc = 0; kc < 4; ++kc)
            bfr[c][kc] = Wf4[((2 * wave + c) * 4 + kc) * 64 + lane];

    U16 afr[4];
    {
        const ushort* ap = z + (size_t)rowA * HD + quad * 8;
#pragma unroll
        for (int kc = 0; kc < 4; ++kc)
            afr[kc].u = *(const uint4*)(ap + kc * 32);
    }

    if (t < HD) {
        float s = 0.f, q = 0.f;
#pragma unroll
        for (int i = 0; i < NSPLIT; ++i) { s += ssum_p[i * HD + t]; q += ssq_p[i * HD + t]; }
        float mean = s / (float)NNODES;
        float var = q / (float)NNODES - mean * mean;
        float rstd = rsqrtf(var + BN_EPS);
        float sc = gamma[t] * rstd;
        sca[t] = sc;
        shf[t] = beta[t] - mean * sc;
    }
    __syncthreads();

#pragma unroll
    for (int kc = 0; kc < 4; ++kc) {
        float f[8];
        unpack8(afr[kc].u, f);
        int kb = kc * 32 + quad * 8;
        float4 s0 = ((const float4*)(sca + kb))[0];
        float4 s1 = ((const float4*)(sca + kb))[1];
        float4 h0 = ((const float4*)(shf + kb))[0];
        float4 h1 = ((const float4*)(shf + kb))[1];
        f[0] = fmaxf(fmaf(f[0], s0.x, h0.x), 0.f);
        f[1] = fmaxf(fmaf(f[1], s0.y, h0.y), 0.f);
        f[2] = fmaxf(fmaf(f[2], s0.z, h0.z), 0.f);
        f[3] = fmaxf(fmaf(f[3], s0.w, h0.w), 0.f);
        f[4] = fmaxf(fmaf(f[4], s1.x, h1.x), 0.f);
        f[5] = fmaxf(fmaf(f[5], s1.y, h1.y), 0.f);
        f[6] = fmaxf(fmaf(f[6], s1.z, h1.z), 0.f);
        f[7] = fmaxf(fmaf(f[7], s1.w, h1.w), 0.f);
        afr[kc].u = pack8(f);
    }

    floatx4 zf = {0.f, 0.f, 0.f, 0.f};
    floatx4 acc[2] = {zf, zf};
#pragma unroll
    for (int kc = 0; kc < 4; ++kc)
#pragma unroll
        for (int c = 0; c < 2; ++c) {
            U16 bu; bu.u = bfr[c][kc];
            acc[c] = __builtin_amdgcn_mfma_f32_16x16x32_bf16(afr[kc].h, bu.h, acc[c], 0, 0, 0);
        }

    int r_base = row0 + quad * 4;
    int lo = 0, hi = NG - 1;
    while (lo < hi) {
        int mid = (lo + hi) >> 1;
        if (r_base >= gptr[mid + 1]) lo = mid + 1; else hi = mid;
    }
    int segr[4];
    int sg = lo;
#pragma unroll
    for (int reg = 0; reg < 4; ++reg) {
        while (r_base + reg >= gptr[sg + 1]) ++sg;
        segr[reg] = sg;
    }
#pragma unroll
    for (int c = 0; c < 2; ++c) {
        int col = (2 * wave + c) * 16 + l16;
        float b = biasB[col];
        float run = 0.f;
        int cur = segr[0];
#pragma unroll
        for (int reg = 0; reg < 4; ++reg) {
            if (segr[reg] != cur) {
                if (run != 0.f) atomicAdd(&gout[cur * HD + col], run);
                run = 0.f;
                cur = segr[reg];
            }
            run += fmaxf(acc[c][reg] + b, 0.f);
        }
        if (run != 0.f) atomicAdd(&gout[cur * HD + col], run);
    }
}

// ---------------- launch ----------------

extern "C" void kernel_launch(void* const* d_in, const int* in_sizes, int n_in,
                              void* d_out, int out_size, void* d_ws, size_t ws_size,
                              hipStream_t stream) {
    const float* x = (const float*)d_in[0];
    const int* esrc = (const int*)d_in[1];
    const int* edst = (const int*)d_in[2];
    const int* gptr = (const int*)d_in[3];
    const float* wA[3] = {(const float*)d_in[4], (const float*)d_in[10], (const float*)d_in[16]};
    const float* bA[3] = {(const float*)d_in[5], (const float*)d_in[11], (const float*)d_in[17]};
    const float* gm[3] = {(const float*)d_in[6], (const float*)d_in[12], (const float*)d_in[18]};
    const float* bt[3] = {(const float*)d_in[7], (const float*)d_in[13], (const float*)d_in[19]};
    const float* wB[3] = {(const float*)d_in[8], (const float*)d_in[14], (const float*)d_in[20]};
    const float* bB[3] = {(const float*)d_in[9], (const float*)d_in[15], (const float*)d_in[21]};

    char* w = (char*)d_ws;
    ushort* ybuf = (ushort*)w; w += (size_t)NNODES * HD * 2;  // 12.8 MB
    ushort* zbuf = (ushort*)w; w += (size_t)NNODES * HD * 2;  // 12.8 MB
    ushort* wf   = (ushort*)w; w += (size_t)6 * 16384 * 2;    // 192 KB
    int* colv  = (int*)w;   w += (size_t)NEDGES * 4;
    int* rank  = (int*)w;   w += (size_t)NEDGES * 4;
    int* incl  = (int*)w;   w += (size_t)NNODES * 4;
    int* rowp  = (int*)w;   w += ((size_t)(NNODES + 1) * 4 + 15) & ~(size_t)15;
    int* bsum  = (int*)w;   w += 64 * 4;
    // ---- zero region ----
    char* zero_base = w;
    int* cnt   = (int*)w;   w += (size_t)NNODES * 4;
    float* ssum_p = (float*)w; w += 3 * NSPLIT * 128 * 4;
    float* ssq_p  = (float*)w; w += 3 * NSPLIT * 128 * 4;
    size_t zero_bytes = (size_t)(w - zero_base);

    hipMemsetAsync(zero_base, 0, zero_bytes, stream);
    hipMemsetAsync(d_out, 0, (size_t)NG * HD * 4, stream);

    WP6 wp;
    wp.w[0] = wA[0]; wp.w[1] = wB[0]; wp.w[2] = wA[1];
    wp.w[3] = wB[1]; wp.w[4] = wA[2]; wp.w[5] = wB[2];

    prep_kernel<<<3131, 256, 0, stream>>>(edst, cnt, rank, wp, wf);
    scan1_kernel<<<NSB, 1024, 0, stream>>>(cnt, incl, bsum, NNODES);
    scan23_kernel<<<(NNODES + 255) / 256, 256, 0, stream>>>(incl, bsum, rowp, NNODES);
    build_kernel<<<(NEDGES + 255) / 256, 256, 0, stream>>>(esrc, edst, rowp, rank, colv, NEDGES);

    // y0 = x @ Wa0
    gemm0A_kernel<<<NTILE, 256, 0, stream>>>(x, wf, ybuf);

    for (int l = 0; l < 3; ++l) {
        agg_kernel<<<NTILE, 256, 0, stream>>>(
            ybuf, rowp, colv, bA[l], zbuf,
            ssum_p + l * NSPLIT * 128, ssq_p + l * NSPLIT * 128);
        if (l < 2) {
            gemmBA_kernel<<<NTILE, 256, 0, stream>>>(
                zbuf, wf + (size_t)(2 * l + 1) * 16384, wf + (size_t)(2 * l + 2) * 16384,
                bB[l], ybuf, gm[l], bt[l],
                ssum_p + l * NSPLIT * 128, ssq_p + l * NSPLIT * 128);
        } else {
            gemmB2_kernel<<<NTILE, 256, 0, stream>>>(
                zbuf, wf + (size_t)(2 * l + 1) * 16384, bB[l], gm[l], bt[l],
                ssum_p + l * NSPLIT * 128, ssq_p + l * NSPLIT * 128,
                gptr, (float*)d_out);
        }
    }
}